// Round 1
// baseline (492.703 us; speedup 1.0000x reference)
//
#include <hip/hip_runtime.h>

typedef __attribute__((ext_vector_type(4))) float f32x4;
typedef __attribute__((ext_vector_type(8))) short bf16x8;
typedef __attribute__((ext_vector_type(4))) int i32x4;

#define LOG2E 1.44269504088896f

__device__ __forceinline__ unsigned short f2bf(float f) {
    unsigned int u = __float_as_uint(f);
    u = (u + 0x7FFFu + ((u >> 16) & 1u)) >> 16;   // RNE
    return (unsigned short)u;
}

__device__ __forceinline__ f32x4 mfma16(bf16x8 a, bf16x8 b, f32x4 c) {
    return __builtin_amdgcn_mfma_f32_16x16x32_bf16(a, b, c, 0, 0, 0);
}

// ---------------- kernel 1: x + pos_emb -> bf16 ----------------
// 9437184 elems, 8 per thread -> 4608 blocks x 256
__global__ void prep_x(const float* __restrict__ x, const float* __restrict__ pos,
                       unsigned short* __restrict__ xb) {
    int t = blockIdx.x * 256 + threadIdx.x;
    int e = t * 8;
    int row  = e >> 8;            // 256 per row
    int prow = row % 2304;
    int col  = e & 255;
    const float4* xp = (const float4*)(x + e);
    const float4* pp = (const float4*)(pos + prow * 256 + col);
    float4 a0 = xp[0], a1 = xp[1];
    float4 p0 = pp[0], p1 = pp[1];
    bf16x8 o;
    o[0] = (short)f2bf(a0.x + p0.x);  o[1] = (short)f2bf(a0.y + p0.y);
    o[2] = (short)f2bf(a0.z + p0.z);  o[3] = (short)f2bf(a0.w + p0.w);
    o[4] = (short)f2bf(a1.x + p1.x);  o[5] = (short)f2bf(a1.y + p1.y);
    o[6] = (short)f2bf(a1.z + p1.z);  o[7] = (short)f2bf(a1.w + p1.w);
    *(bf16x8*)(xb + e) = o;
}

// ---------------- kernel 2: pack weights transposed + biases ----------------
// wT[n][k] (n=0..767, k=0..255), bias[768].  196608 threads.
__global__ void prep_w(const float* __restrict__ wq, const float* __restrict__ wk,
                       const float* __restrict__ wv, const float* __restrict__ bq,
                       const float* __restrict__ bk, const float* __restrict__ bv,
                       unsigned short* __restrict__ wT, float* __restrict__ bias) {
    int t = blockIdx.x * 256 + threadIdx.x;   // 0..196607
    int n = t >> 8, k = t & 255;
    const float* w = (n < 256) ? wq : (n < 512) ? wk : wv;
    int col = n & 255;
    wT[t] = f2bf(w[k * 256 + col]);
    if (t < 768) {
        const float* bs = (t < 256) ? bq : (t < 512) ? bk : bv;
        bias[t] = bs[t & 255];
    }
}

// ---------------- kernel 3: QKV GEMM ----------------
// C[36864][768] = xb[36864][256] @ wqkv[256][768] + bias
// tile 64x64, BK=64, 4 waves, 16x16x32 MFMA.
// outputs: q,k row-major bf16 [36864][256]; v transposed: vt[b][d][s] bf16.
__global__ __launch_bounds__(256)
void qkv_gemm(const unsigned short* __restrict__ xb,
              const unsigned short* __restrict__ wT,
              const float* __restrict__ bias,
              unsigned short* __restrict__ qb,
              unsigned short* __restrict__ kb,
              unsigned short* __restrict__ vtb) {
    __shared__ __align__(16) unsigned short Al[64 * 64];
    __shared__ __align__(16) unsigned short Bl[64 * 64];
    int rm0 = blockIdx.y * 64;
    int bn0 = blockIdx.x * 64;
    int tid = threadIdx.x;
    int lane = tid & 63, w = tid >> 6;
    int l15 = lane & 15, l4 = lane >> 4;

    f32x4 acc[4] = {};
    for (int k0 = 0; k0 < 256; k0 += 64) {
        __syncthreads();
        #pragma unroll
        for (int i = 0; i < 2; ++i) {
            int c = i * 256 + tid;        // 0..511 (16B chunks)
            int r = c >> 3, cc = c & 7;
            i32x4 av = *(const i32x4*)(xb + (long)(rm0 + r) * 256 + k0 + cc * 8);
            *(i32x4*)((char*)Al + r * 128 + ((cc * 16) ^ ((r & 7) << 4))) = av;
            i32x4 bv = *(const i32x4*)(wT + (long)(bn0 + r) * 256 + k0 + cc * 8);
            *(i32x4*)((char*)Bl + r * 128 + ((cc * 16) ^ ((r & 7) << 4))) = bv;
        }
        __syncthreads();
        int arow = w * 16 + l15;
        #pragma unroll
        for (int kk = 0; kk < 2; ++kk) {
            bf16x8 a = *(const bf16x8*)((char*)Al + arow * 128 +
                        ((kk * 64 + l4 * 16) ^ ((arow & 7) << 4)));
            #pragma unroll
            for (int nb = 0; nb < 4; ++nb) {
                int brow = nb * 16 + l15;
                bf16x8 b = *(const bf16x8*)((char*)Bl + brow * 128 +
                            ((kk * 64 + l4 * 16) ^ ((brow & 7) << 4)));
                acc[nb] = mfma16(a, b, acc[nb]);
            }
        }
    }
    // epilogue
    int bidx  = rm0 / 2304;                       // batch (rm0 multiple of 64; 2304%64==0)
    int grow0 = rm0 + w * 16 + l4 * 4;
    int srow0 = grow0 - bidx * 2304;
    #pragma unroll
    for (int nb = 0; nb < 4; ++nb) {
        int n = bn0 + nb * 16 + l15;
        float bs = bias[n];
        #pragma unroll
        for (int j = 0; j < 4; ++j) {
            unsigned short h = f2bf(acc[nb][j] + bs);
            int grow = grow0 + j;
            if (n < 256)       qb[(long)grow * 256 + n] = h;
            else if (n < 512)  kb[(long)grow * 256 + (n - 256)] = h;
            else               vtb[((long)bidx * 256 + (n - 512)) * 2304 + (srow0 + j)] = h;
        }
    }
}

// ---------------- kernel 4: flash attention ----------------
// grid (36 q-tiles, 16 batches), 256 threads (4 waves, 16 q-rows each).
__global__ __launch_bounds__(256)
void attn(const unsigned short* __restrict__ qb,
          const unsigned short* __restrict__ kbuf,
          const unsigned short* __restrict__ vtb,
          float* __restrict__ out) {
    __shared__ __align__(16) unsigned short Kl[64 * 256];   // 32KB, swizzled 512B rows
    __shared__ __align__(16) unsigned short Vl[256 * 64];   // 32KB, swizzled 128B rows
    int b = blockIdx.y, q0 = blockIdx.x * 64;
    int tid = threadIdx.x;
    int lane = tid & 63, w = tid >> 6;
    int l15 = lane & 15, l4 = lane >> 4;

    // Q fragments in registers: rows w*16+l15, all 256 dims
    bf16x8 qf[8];
    {
        const unsigned short* qrow = qb + (long)(b * 2304 + q0 + w * 16 + l15) * 256;
        #pragma unroll
        for (int kbk = 0; kbk < 8; ++kbk)
            qf[kbk] = *(const bf16x8*)(qrow + kbk * 32 + l4 * 8);
    }

    f32x4 o[16] = {};
    float m[4]  = {-__builtin_inff(), -__builtin_inff(), -__builtin_inff(), -__builtin_inff()};
    float ls[4] = {0.f, 0.f, 0.f, 0.f};

    const unsigned short* kg0 = kbuf + (long)b * 2304 * 256;
    const unsigned short* vg0 = vtb + (long)b * 256 * 2304;

    for (int t = 0; t < 36; ++t) {
        int kv0 = t * 64;
        __syncthreads();   // previous tile's LDS reads done before overwrite
        // stage K tile [64][256]
        const unsigned short* kg = kg0 + (long)kv0 * 256;
        #pragma unroll
        for (int i = 0; i < 8; ++i) {
            int c = i * 256 + tid;          // 2048 16B chunks
            int r = c >> 5, cc = c & 31;
            i32x4 v = *(const i32x4*)(kg + r * 256 + cc * 8);
            *(i32x4*)((char*)Kl + r * 512 + ((cc * 16) ^ ((r & 7) << 4))) = v;
        }
        // stage V^T tile [256][64]
        #pragma unroll
        for (int i = 0; i < 8; ++i) {
            int c = i * 256 + tid;          // 2048 16B chunks
            int r = c >> 3, cc = c & 7;     // r = dim
            i32x4 v = *(const i32x4*)(vg0 + (long)r * 2304 + kv0 + cc * 8);
            *(i32x4*)((char*)Vl + r * 128 + ((cc * 16) ^ ((r & 7) << 4))) = v;
        }
        __syncthreads();

        // S = Q K^T  (16 q-rows x 64 kv)
        f32x4 s[4] = {};
        #pragma unroll
        for (int cb = 0; cb < 4; ++cb) {
            int krow = cb * 16 + l15;
            #pragma unroll
            for (int kbk = 0; kbk < 8; ++kbk) {
                bf16x8 kf = *(const bf16x8*)((char*)Kl + krow * 512 +
                             ((kbk * 64 + l4 * 16) ^ ((krow & 7) << 4)));
                s[cb] = mfma16(qf[kbk], kf, s[cb]);
            }
        }

        // online softmax (rows = l4*4+j, cols spread over l15 and cb)
        float pr[4][4];
        #pragma unroll
        for (int cb = 0; cb < 4; ++cb)
            #pragma unroll
            for (int j = 0; j < 4; ++j)
                pr[cb][j] = s[cb][j] * 0.0625f;

        float alpha[4];
        #pragma unroll
        for (int j = 0; j < 4; ++j) {
            float mx = fmaxf(fmaxf(pr[0][j], pr[1][j]), fmaxf(pr[2][j], pr[3][j]));
            #pragma unroll
            for (int msk = 1; msk < 16; msk <<= 1)
                mx = fmaxf(mx, __shfl_xor(mx, msk));
            float mn = fmaxf(m[j], mx);
            alpha[j] = exp2f((m[j] - mn) * LOG2E);
            m[j] = mn;
            float rs = 0.f;
            #pragma unroll
            for (int cb = 0; cb < 4; ++cb) {
                float p = exp2f((pr[cb][j] - mn) * LOG2E);
                pr[cb][j] = p;
                rs += p;
            }
            #pragma unroll
            for (int msk = 1; msk < 16; msk <<= 1)
                rs += __shfl_xor(rs, msk);
            ls[j] = ls[j] * alpha[j] + rs;
        }
        #pragma unroll
        for (int nb = 0; nb < 16; ++nb)
            #pragma unroll
            for (int j = 0; j < 4; ++j)
                o[nb][j] *= alpha[j];

        // K tile is dead now; reuse its first 8KB as per-wave P scratch.
        __syncthreads();   // ensure all waves finished reading Kl
        char* pbase = (char*)Kl + w * 2048;   // [16 rows][128B], swizzled
        #pragma unroll
        for (int cb = 0; cb < 4; ++cb)
            #pragma unroll
            for (int j = 0; j < 4; ++j) {
                int R = l4 * 4 + j;
                int colb = l15 * 2 + cb * 32;
                *(unsigned short*)(pbase + R * 128 + (colb ^ ((R & 7) << 4))) = f2bf(pr[cb][j]);
            }
        bf16x8 pf[2];
        #pragma unroll
        for (int kk = 0; kk < 2; ++kk)
            pf[kk] = *(const bf16x8*)(pbase + l15 * 128 +
                      ((kk * 64 + l4 * 16) ^ ((l15 & 7) << 4)));

        // O += P V   (16 x 64) @ (64 x 256)
        #pragma unroll
        for (int nb = 0; nb < 16; ++nb) {
            int vrow = nb * 16 + l15;
            #pragma unroll
            for (int kk = 0; kk < 2; ++kk) {
                bf16x8 vf = *(const bf16x8*)((char*)Vl + vrow * 128 +
                             ((kk * 64 + l4 * 16) ^ ((vrow & 7) << 4)));
                o[nb] = mfma16(pf[kk], vf, o[nb]);
            }
        }
    }

    // epilogue: O / l
    float inv[4];
    #pragma unroll
    for (int j = 0; j < 4; ++j) inv[j] = 1.0f / ls[j];
    long obase = ((long)b * 2304 + q0 + w * 16) * 256;
    #pragma unroll
    for (int nb = 0; nb < 16; ++nb)
        #pragma unroll
        for (int j = 0; j < 4; ++j)
            out[obase + (long)(l4 * 4 + j) * 256 + nb * 16 + l15] = o[nb][j] * inv[j];
}

extern "C" void kernel_launch(void* const* d_in, const int* in_sizes, int n_in,
                              void* d_out, int out_size, void* d_ws, size_t ws_size,
                              hipStream_t stream) {
    const float* x   = (const float*)d_in[0];
    const float* wq  = (const float*)d_in[1];
    const float* bq  = (const float*)d_in[2];
    const float* wk  = (const float*)d_in[3];
    const float* bk  = (const float*)d_in[4];
    const float* wv  = (const float*)d_in[5];
    const float* bv  = (const float*)d_in[6];
    const float* pos = (const float*)d_in[7];

    const long NROW = 36864;            // 16*2304
    unsigned short* xb  = (unsigned short*)d_ws;
    unsigned short* qbf = xb  + NROW * 256;
    unsigned short* kbf = qbf + NROW * 256;
    unsigned short* vtb = kbf + NROW * 256;
    unsigned short* wT  = vtb + NROW * 256;
    float* bias = (float*)(wT + 768 * 256);

    prep_x<<<4608, 256, 0, stream>>>(x, pos, xb);
    prep_w<<<768, 256, 0, stream>>>(wq, wk, wv, bq, bk, bv, wT, bias);
    qkv_gemm<<<dim3(12, 576), 256, 0, stream>>>(xb, wT, bias, qbf, kbf, vtb);
    attn<<<dim3(36, 16), 256, 0, stream>>>(qbf, kbf, vtb, (float*)d_out);
}